// Round 3
// baseline (587.662 us; speedup 1.0000x reference)
//
#include <hip/hip_runtime.h>
#include <hip/hip_bf16.h>

#define B_IMG 8192

// ---- ws layout (bytes) ----
#define OFF_STATS 0                        // 8 doubles (sum, sumsq per channel)
#define OFF_SD    64                       // 1 float (RBF sum of squares)
#define OFF_PROJ  128                      // 8192*4 doubles = 262144
#define OFF_PN64  (128 + 262144)           // 8192*4 doubles
#define OFF_PB32  (OFF_PN64 + 262144)      // 8192*4 floats
#define OFF_PN32  (OFF_PB32 + 131072)
#define OFF_WP32  (OFF_PN32 + 131072)
#define OFF_W2R   (OFF_WP32 + 131072)      // 1152 doubles (conv2 w relayout)
#define OFF_FLAT  1048576                  // flat: f64 (51.4MB) or f32 (25.7MB)
#define FLAT64_BYTES (8192UL * 784UL * 8UL)

// ---------------------------------------------------------------------------
// Kernel 0: setup — zero accumulators; relayout conv2 weights to f64
// [c][ic][ky][kx] -> [c][ky*3+kx][ic]
// ---------------------------------------------------------------------------
__global__ __launch_bounds__(256) void setup_kernel(
    const float* __restrict__ w2, double* __restrict__ w2r,
    double* __restrict__ stats, float* __restrict__ sd) {
    const int t = threadIdx.x;
    if (t < 8) stats[t] = 0.0;
    if (t == 0) sd[0] = 0.f;
    for (int i = t; i < 1152; i += 256) {
        int kx = i % 3, ky = (i / 3) % 3, ic = (i / 9) % 8, c = i / 72;
        w2r[(c * 9 + ky * 3 + kx) * 8 + ic] = (double)w2[i];
    }
}

// ---------------------------------------------------------------------------
// Kernel 1: fused conv1+relu+pool -> conv2+relu+pool, all f64 compute.
// One image per 256-thread block. Zero-padded LDS halos; no bounds checks.
// flat[b][c*49+y*7+x] stored f64 (primary) or f32 (small-ws fallback).
// ---------------------------------------------------------------------------
template <bool F64OUT>
__global__ __launch_bounds__(256) void conv_fused(
    const float* __restrict__ x,
    const float* __restrict__ w1, const float* __restrict__ b1,
    const double* __restrict__ w2r, const float* __restrict__ b2,
    void* __restrict__ flatv) {

    __shared__ __align__(16) float  xs[900];          // padded 30x30 f32 (input vals)
    __shared__ __align__(16) double h1s[16][16][8];   // padded 14x14, [y][x][ic] f64
    __shared__ __align__(16) double h2s[784];         // [c][7][7] f64
    __shared__ __align__(16) double w2v[16 * 73];     // [c][tap*8+ic], pad 73 (banks)
    __shared__ double w1s[72];
    __shared__ double b1s[8];
    __shared__ double b2s[16];

    const int b = blockIdx.x;
    const int t = threadIdx.x;
    const float* xb = x + (size_t)b * 784;

    // phase A: zero padded buffers, stage weights (f32 -> f64)
    for (int i = t; i < 900; i += 256) xs[i] = 0.f;
    {
        double* h1f = &h1s[0][0][0];
        for (int i = t; i < 2048; i += 256) h1f[i] = 0.0;
    }
    for (int i = t; i < 1152; i += 256) {
        int c = i / 72, r = i % 72;
        w2v[c * 73 + r] = w2r[i];
    }
    if (t < 72) w1s[t] = (double)w1[t];
    if (t < 8)  b1s[t] = (double)b1[t];
    if (t < 16) b2s[t] = (double)b2[t];
    __syncthreads();
    // phase B: fill xs interior
    for (int i = t; i < 784; i += 256) {
        const int yy = i / 28, xx = i - yy * 28;
        xs[(yy + 1) * 30 + (xx + 1)] = xb[i];
    }
    __syncthreads();

    // ---- stage 1: conv1 + relu + maxpool (f64) -> h1s interior
    {
        const int c1 = t & 7;
        double wc[9];
#pragma unroll
        for (int j = 0; j < 9; ++j) wc[j] = w1s[c1 * 9 + j];
        const double bb = b1s[c1];
        for (int q = (t >> 3); q < 196; q += 32) {
            const int py = q / 14, px = q - py * 14;
            double r2[4][4];
#pragma unroll
            for (int rr = 0; rr < 4; ++rr)
#pragma unroll
                for (int cc = 0; cc < 4; ++cc)
                    r2[rr][cc] = (double)xs[(2 * py + rr) * 30 + 2 * px + cc];
            double s[2][2] = {{bb, bb}, {bb, bb}};
#pragma unroll
            for (int dy = 0; dy < 2; ++dy)
#pragma unroll
                for (int dx = 0; dx < 2; ++dx)
#pragma unroll
                    for (int ky = 0; ky < 3; ++ky)
#pragma unroll
                        for (int kx = 0; kx < 3; ++kx)
                            s[dy][dx] = fma(r2[dy + ky][dx + kx], wc[ky * 3 + kx], s[dy][dx]);
            double mx = fmax(fmax(s[0][0], s[0][1]), fmax(s[1][0], s[1][1]));
            mx = fmax(mx, 0.0);   // pool(relu) == relu(maxpool)
            h1s[py + 1][px + 1][c1] = mx;
        }
    }
    __syncthreads();

    // ---- stage 2: conv2 + relu + maxpool (f64) -> h2s [16][49]
    {
        const int c2 = t & 15;
        const double bias2 = b2s[c2];
        const double* wbase = &w2v[c2 * 73];
        for (int q = (t >> 4); q < 49; q += 16) {
            const int py = q / 7, px = q - py * 7;
            double s[2][2] = {{bias2, bias2}, {bias2, bias2}};
#pragma unroll
            for (int rr = 0; rr < 4; ++rr)
#pragma unroll
                for (int cc = 0; cc < 4; ++cc) {
                    const double* hp = &h1s[2 * py + rr][2 * px + cc][0];
                    double2 v01 = *(const double2*)&hp[0];
                    double2 v23 = *(const double2*)&hp[2];
                    double2 v45 = *(const double2*)&hp[4];
                    double2 v67 = *(const double2*)&hp[6];
#pragma unroll
                    for (int dy = 0; dy < 2; ++dy) {
                        const int ky = rr - dy;
                        if (ky < 0 || ky > 2) continue;   // constant-folds
#pragma unroll
                        for (int dx = 0; dx < 2; ++dx) {
                            const int kx = cc - dx;
                            if (kx < 0 || kx > 2) continue;
                            const double* wp_ = &wbase[(ky * 3 + kx) * 8];
                            double2 w01 = *(const double2*)&wp_[0];
                            double2 w23 = *(const double2*)&wp_[2];
                            double2 w45 = *(const double2*)&wp_[4];
                            double2 w67 = *(const double2*)&wp_[6];
                            double acc = s[dy][dx];
                            acc = fma(v01.x, w01.x, acc);
                            acc = fma(v01.y, w01.y, acc);
                            acc = fma(v23.x, w23.x, acc);
                            acc = fma(v23.y, w23.y, acc);
                            acc = fma(v45.x, w45.x, acc);
                            acc = fma(v45.y, w45.y, acc);
                            acc = fma(v67.x, w67.x, acc);
                            acc = fma(v67.y, w67.y, acc);
                            s[dy][dx] = acc;
                        }
                    }
                }
            double mx = fmax(fmax(s[0][0], s[0][1]), fmax(s[1][0], s[1][1]));
            mx = fmax(mx, 0.0);
            h2s[c2 * 49 + q] = mx;
        }
    }
    __syncthreads();

    // writeout
    if (F64OUT) {
        double2* dst = (double2*)((double*)flatv + (size_t)b * 784);
        const double2* src = (const double2*)h2s;
        for (int i = t; i < 392; i += 256) dst[i] = src[i];
    } else {
        float* dst = (float*)flatv + (size_t)b * 784;
        for (int i = t; i < 784; i += 256) dst[i] = (float)h2s[i];
    }
}

// ---------------------------------------------------------------------------
// Kernel 2: FC1 (784->64, relu) + FC2 (64->4) + BN batch-stat partials, f64.
// Tile 32 rows x 64 cols, K-step 16, 256 threads.
// ---------------------------------------------------------------------------
template <bool F64IN>
__global__ __launch_bounds__(256) void fc_kernel(
    const void* __restrict__ flatv,
    const float* __restrict__ fc1w, const float* __restrict__ fc1b,
    const float* __restrict__ fc2w, const float* __restrict__ fc2b,
    double* __restrict__ proj, double* __restrict__ stats) {

    __shared__ __align__(16) double As[32][18];   // pad 18: bank-spread
    __shared__ __align__(16) double Bs[16][68];   // pad 68
    __shared__ __align__(16) double Hs[32][66];
    __shared__ double w2t[256];   // [c][kc] fc2 transposed
    __shared__ double b1s[64];
    __shared__ double b2s[4];

    const int t = threadIdx.x;
    const int row0 = blockIdx.x * 32;

    w2t[t] = (double)fc2w[(t & 3) * 64 + (t >> 2)];
    if (t < 64) b1s[t] = (double)fc1b[t];
    if (t < 4)  b2s[t] = (double)fc2b[t];

    const int tx = t & 15, ty = t >> 4;
    double acc[2][4] = {};

    const int ar = t >> 3, ak = (t * 2) & 15;
    const int bo = t >> 2, bk4 = (t & 3) * 4;

    for (int kk = 0; kk < 784; kk += 16) {
        double2 av;
        if (F64IN) {
            av = *(const double2*)((const double*)flatv + (size_t)(row0 + ar) * 784 + kk + ak);
        } else {
            float2 f = *(const float2*)((const float*)flatv + (size_t)(row0 + ar) * 784 + kk + ak);
            av.x = (double)f.x; av.y = (double)f.y;
        }
        float4 bv = *(const float4*)&fc1w[(size_t)bo * 784 + kk + bk4];
        __syncthreads();
        *(double2*)&As[ar][ak] = av;
        Bs[bk4 + 0][bo] = (double)bv.x; Bs[bk4 + 1][bo] = (double)bv.y;
        Bs[bk4 + 2][bo] = (double)bv.z; Bs[bk4 + 3][bo] = (double)bv.w;
        __syncthreads();
#pragma unroll
        for (int k4 = 0; k4 < 4; ++k4) {
            double2 a0l = *(const double2*)&As[ty * 2 + 0][k4 * 4];
            double2 a0h = *(const double2*)&As[ty * 2 + 0][k4 * 4 + 2];
            double2 a1l = *(const double2*)&As[ty * 2 + 1][k4 * 4];
            double2 a1h = *(const double2*)&As[ty * 2 + 1][k4 * 4 + 2];
            double a0a[4] = {a0l.x, a0l.y, a0h.x, a0h.y};
            double a1a[4] = {a1l.x, a1l.y, a1h.x, a1h.y};
#pragma unroll
            for (int k = 0; k < 4; ++k) {
                double2 bl = *(const double2*)&Bs[k4 * 4 + k][tx * 4];
                double2 bh = *(const double2*)&Bs[k4 * 4 + k][tx * 4 + 2];
                acc[0][0] = fma(a0a[k], bl.x, acc[0][0]);
                acc[0][1] = fma(a0a[k], bl.y, acc[0][1]);
                acc[0][2] = fma(a0a[k], bh.x, acc[0][2]);
                acc[0][3] = fma(a0a[k], bh.y, acc[0][3]);
                acc[1][0] = fma(a1a[k], bl.x, acc[1][0]);
                acc[1][1] = fma(a1a[k], bl.y, acc[1][1]);
                acc[1][2] = fma(a1a[k], bh.x, acc[1][2]);
                acc[1][3] = fma(a1a[k], bh.y, acc[1][3]);
            }
        }
    }

#pragma unroll
    for (int i2 = 0; i2 < 2; ++i2)
#pragma unroll
        for (int j = 0; j < 4; ++j) {
            const int c = tx * 4 + j;
            Hs[ty * 2 + i2][c] = fmax(acc[i2][j] + b1s[c], 0.0);
        }
    __syncthreads();

    if (t < 128) {
        const int r = t >> 2, kc = t & 3;
        double s = b2s[kc];
#pragma unroll 8
        for (int c = 0; c < 64; ++c) s = fma(Hs[r][c], w2t[c * 4 + kc], s);
        proj[(size_t)(row0 + r) * 4 + kc] = s;
        double ssum = s, sq = s * s;
#pragma unroll
        for (int m = 4; m < 64; m <<= 1) {
            ssum += __shfl_xor(ssum, m);
            sq   += __shfl_xor(sq, m);
        }
        if ((t & 63) < 4) {
            atomicAdd(&stats[kc], ssum);
            atomicAdd(&stats[4 + kc], sq);
        }
    }
}

// ---------------------------------------------------------------------------
// Kernel 3: BatchNorm + row L2-normalize, f64. Emits pb32/pn32 (fast path)
// and pn64 (exact path for borderline fid rechecks).
// ---------------------------------------------------------------------------
__global__ __launch_bounds__(256) void bn_kernel(
    const double* __restrict__ proj, const double* __restrict__ stats,
    const float* __restrict__ gamma, const float* __restrict__ beta,
    float* __restrict__ pb32, float* __restrict__ pn32,
    double* __restrict__ pn64) {

    const int i = blockIdx.x * 256 + threadIdx.x;
    double2 p01 = ((const double2*)proj)[2 * i];
    double2 p23 = ((const double2*)proj)[2 * i + 1];
    double pv[4] = {p01.x, p01.y, p23.x, p23.y};
    double o[4];
#pragma unroll
    for (int k = 0; k < 4; ++k) {
        double mean = stats[k] * (1.0 / 8192.0);
        double var  = stats[4 + k] * (1.0 / 8192.0) - mean * mean;
        double inv  = 1.0 / sqrt(var + 1e-5);
        o[k] = (pv[k] - mean) * inv * (double)gamma[k] + (double)beta[k];
    }
    double nrm = sqrt(o[0] * o[0] + o[1] * o[1] + o[2] * o[2] + o[3] * o[3]);
    double innv = 1.0 / (nrm + 1e-12);
    ((float4*)pb32)[i] = make_float4((float)o[0], (float)o[1], (float)o[2], (float)o[3]);
    double n0 = o[0] * innv, n1 = o[1] * innv, n2 = o[2] * innv, n3 = o[3] * innv;
    ((float4*)pn32)[i] = make_float4((float)n0, (float)n1, (float)n2, (float)n3);
    double2* pd = (double2*)(pn64 + (size_t)i * 4);
    pd[0] = make_double2(n0, n1);
    pd[1] = make_double2(n2, n3);
}

// ---------------------------------------------------------------------------
// Kernel 4: O(B^2) adjacency. fp32 fast path with +-2e-4 guard band around
// 0.9; borderline pairs recheck in f64 from pn64 (exact flip decisions).
// 64 rows/block (4 rows/lane x 16 j-lanes), LDS-staged j chunks of 1024.
// ---------------------------------------------------------------------------
#define CHUNK 1024
__global__ __launch_bounds__(256) void adj_kernel(
    const float* __restrict__ pn32, const float* __restrict__ pb32,
    const double* __restrict__ pn64,
    float* __restrict__ wp32, float* __restrict__ sd) {

    __shared__ __align__(16) float4 pns[CHUNK];
    __shared__ __align__(16) float4 pbs[CHUNK];
    __shared__ float bpart[16];

    const int t = threadIdx.x;
    const int tg = t & 15, g = t >> 4;
    const int rowb = blockIdx.x * 64 + g * 4;

    float4 pni[4];
#pragma unroll
    for (int r = 0; r < 4; ++r) pni[r] = ((const float4*)pn32)[rowb + r];
    float w[4][4] = {};

    for (int base = 0; base < 8192; base += CHUNK) {
        __syncthreads();
        for (int i = t; i < CHUNK; i += 256) {
            pns[i] = ((const float4*)pn32)[base + i];
            pbs[i] = ((const float4*)pb32)[base + i];
        }
        __syncthreads();
        for (int jj = 0; jj < CHUNK / 16; ++jj) {
            const int jl = jj * 16 + tg;
            const int j = base + jl;
            float4 q = pns[jl];
            float4 pj = pbs[jl];
#pragma unroll
            for (int r = 0; r < 4; ++r) {
                float d = fmaf(pni[r].x, q.x, fmaf(pni[r].y, q.y,
                          fmaf(pni[r].z, q.z, pni[r].w * q.w)));
                float fid = d * d;
                bool ok;
                if (fabsf(fid - 0.9f) < 2e-4f) {   // rare: exact recheck
                    const double2* pr = (const double2*)(pn64 + (size_t)(rowb + r) * 4);
                    const double2* pq = (const double2*)(pn64 + (size_t)j * 4);
                    double2 r0 = pr[0], r1 = pr[1], q0 = pq[0], q1 = pq[1];
                    double dd = fma(r0.x, q0.x, fma(r0.y, q0.y,
                                fma(r1.x, q1.x, r1.y * q1.y)));
                    ok = (dd * dd >= 0.9);
                } else {
                    ok = (fid >= 0.9f);
                }
                float m = (ok && j != (rowb + r)) ? 1.f : 0.f;
                w[r][0] = fmaf(m, pj.x, w[r][0]);
                w[r][1] = fmaf(m, pj.y, w[r][1]);
                w[r][2] = fmaf(m, pj.z, w[r][2]);
                w[r][3] = fmaf(m, pj.w, w[r][3]);
            }
        }
    }
#pragma unroll
    for (int m = 1; m < 16; m <<= 1)
#pragma unroll
        for (int r = 0; r < 4; ++r) {
            w[r][0] += __shfl_xor(w[r][0], m);
            w[r][1] += __shfl_xor(w[r][1], m);
            w[r][2] += __shfl_xor(w[r][2], m);
            w[r][3] += __shfl_xor(w[r][3], m);
        }
    if (tg == 0) {
        float ds_ = 0.f;
#pragma unroll
        for (int r = 0; r < 4; ++r) {
            ((float4*)wp32)[rowb + r] = make_float4(w[r][0], w[r][1], w[r][2], w[r][3]);
            float4 pbv = ((const float4*)pb32)[rowb + r];
            float d0 = pbv.x - w[r][0], d1 = pbv.y - w[r][1];
            float d2 = pbv.z - w[r][2], d3 = pbv.w - w[r][3];
            ds_ += d0 * d0 + d1 * d1 + d2 * d2 + d3 * d3;
        }
        bpart[g] = ds_;
    }
    __syncthreads();
    if (t == 0) {
        float s = 0.f;
#pragma unroll
        for (int i = 0; i < 16; ++i) s += bpart[i];
        atomicAdd(sd, s);
    }
}

// ---------------------------------------------------------------------------
// Kernel 5: epilogue -> probs
// ---------------------------------------------------------------------------
__global__ __launch_bounds__(256) void final_kernel(
    const float* __restrict__ pb32, const float* __restrict__ wp32,
    const float* __restrict__ sd, float* __restrict__ out) {

    const int i = blockIdx.x * 256 + threadIdx.x;
    const double kv = exp(-(double)sd[0]);
    float4 p = ((const float4*)pb32)[i];
    float4 w = ((const float4*)wp32)[i];
    double logit = (double)p.x + p.y + p.z + p.w
                 + (double)w.x + w.y + w.z + w.w + kv;
    double pr = 1.0 / (1.0 + exp(-logit));
    *(float2*)&out[2 * i] = make_float2((float)pr, (float)(1.0 - pr));
}

// ---------------------------------------------------------------------------
extern "C" void kernel_launch(void* const* d_in, const int* in_sizes, int n_in,
                              void* d_out, int out_size, void* d_ws, size_t ws_size,
                              hipStream_t stream) {
    const float* x     = (const float*)d_in[0];
    const float* c1w   = (const float*)d_in[1];
    const float* c1b   = (const float*)d_in[2];
    const float* c2w   = (const float*)d_in[3];
    const float* c2b   = (const float*)d_in[4];
    const float* fc1w  = (const float*)d_in[5];
    const float* fc1b  = (const float*)d_in[6];
    const float* fc2w  = (const float*)d_in[7];
    const float* fc2b  = (const float*)d_in[8];
    const float* gamma = (const float*)d_in[9];
    const float* beta  = (const float*)d_in[10];
    float* out = (float*)d_out;

    char* ws = (char*)d_ws;
    double* stats = (double*)(ws + OFF_STATS);
    float*  sd    = (float*)(ws + OFF_SD);
    double* proj  = (double*)(ws + OFF_PROJ);
    double* pn64  = (double*)(ws + OFF_PN64);
    float*  pb32  = (float*)(ws + OFF_PB32);
    float*  pn32  = (float*)(ws + OFF_PN32);
    float*  wp32  = (float*)(ws + OFF_WP32);
    double* w2r   = (double*)(ws + OFF_W2R);
    void*   flat  = (void*)(ws + OFF_FLAT);

    // deterministic per-deployment branch (ws_size is constant across calls)
    const bool f64flat = ws_size >= (size_t)OFF_FLAT + FLAT64_BYTES;

    setup_kernel<<<1, 256, 0, stream>>>(c2w, w2r, stats, sd);
    if (f64flat) {
        conv_fused<true><<<B_IMG, 256, 0, stream>>>(x, c1w, c1b, w2r, c2b, flat);
        fc_kernel<true><<<B_IMG / 32, 256, 0, stream>>>(flat, fc1w, fc1b, fc2w, fc2b, proj, stats);
    } else {
        conv_fused<false><<<B_IMG, 256, 0, stream>>>(x, c1w, c1b, w2r, c2b, flat);
        fc_kernel<false><<<B_IMG / 32, 256, 0, stream>>>(flat, fc1w, fc1b, fc2w, fc2b, proj, stats);
    }
    bn_kernel<<<B_IMG / 256, 256, 0, stream>>>(proj, stats, gamma, beta, pb32, pn32, pn64);
    adj_kernel<<<B_IMG / 64, 256, 0, stream>>>(pn32, pb32, pn64, wp32, sd);
    final_kernel<<<B_IMG / 256, 256, 0, stream>>>(pb32, wp32, sd, out);
}

// Round 4
// 504.803 us; speedup vs baseline: 1.1641x; 1.1641x over previous
//
#include <hip/hip_runtime.h>
#include <hip/hip_bf16.h>

#define B_IMG 8192
#define FC_ROWS 4
#define FC_NBLK (B_IMG / FC_ROWS)   // 2048

// ---- ws layout (bytes) ----
#define OFF_STATS 0                        // 8 doubles (sum, sumsq per channel)
#define OFF_SD    64                       // 1 float (RBF sum of squares)
#define OFF_PROJ  128                      // 8192*4 doubles = 262144
#define OFF_PN64  (128 + 262144)           // 8192*4 doubles
#define OFF_PB32  (OFF_PN64 + 262144)      // 8192*4 floats
#define OFF_PN32  (OFF_PB32 + 131072)
#define OFF_WP32  (OFF_PN32 + 131072)
#define OFF_W2R   (OFF_WP32 + 131072)      // 1152 doubles = 9216
#define OFF_W1T   (OFF_W2R + 9216)         // 784*64 floats = 200704
#define OFF_PSUM  (OFF_W1T + 200704)       // 2048*8 doubles = 131072
#define OFF_FLAT  1310720                  // flat: f64 (51.4MB) or f32 (25.7MB)
#define FLAT64_BYTES (8192UL * 784UL * 8UL)

// ---------------------------------------------------------------------------
// Kernel 0: setup — zero sd; relayout conv2 weights to f64
// [c][ic][ky][kx] -> [c][ky*3+kx][ic]; transpose fc1w -> w1t[k][o] (f32).
// Grid: 64 blocks x 256.
// ---------------------------------------------------------------------------
__global__ __launch_bounds__(256) void setup_kernel(
    const float* __restrict__ w2, const float* __restrict__ fc1w,
    double* __restrict__ w2r, float* __restrict__ w1t,
    float* __restrict__ sd) {
    const int t = threadIdx.x;
    if (blockIdx.x == 0) {
        if (t == 0) sd[0] = 0.f;
        for (int i = t; i < 1152; i += 256) {
            int kx = i % 3, ky = (i / 3) % 3, ic = (i / 9) % 8, c = i / 72;
            w2r[(c * 9 + ky * 3 + kx) * 8 + ic] = (double)w2[i];
        }
    }
    for (int i = blockIdx.x * 256 + t; i < 784 * 64; i += 64 * 256) {
        const int o = i & 63, k = i >> 6;
        w1t[i] = fc1w[o * 784 + k];     // w1t[k*64+o]
    }
}

// ---------------------------------------------------------------------------
// Kernel 1: fused conv1+relu+pool -> conv2+relu+pool, all f64 compute.
// One image per 256-thread block. conv2 weights in REGISTERS (ic split
// across lane pairs, shfl_xor combine) — no weight LDS traffic.
// flat[b][c*49+y*7+x] stored f64 (primary) or f32 (small-ws fallback).
// ---------------------------------------------------------------------------
#define H1PAD 10   // ic-stride pad: keeps 16B align, spreads banks
template <bool F64OUT>
__global__ __launch_bounds__(256) void conv_fused(
    const float* __restrict__ x,
    const float* __restrict__ w1, const float* __restrict__ b1,
    const double* __restrict__ w2r, const float* __restrict__ b2,
    void* __restrict__ flatv) {

    __shared__ __align__(16) float  xs[900];              // padded 30x30 f32
    __shared__ __align__(16) double h1s[16 * 16 * H1PAD]; // padded 14x14 [y][x][ic]
    __shared__ __align__(16) double h2s[784];             // [c][7][7]

    const int b = blockIdx.x;
    const int t = threadIdx.x;
    const float* xb = x + (size_t)b * 784;

    // stage-2 lane mapping (load weights early: global, L2-cached)
    const int c2 = t >> 4;
    const int icp = (t >> 3) & 1;
    const int g2 = t & 7;
    double wgt[9][4];
    {
        const double* wb = w2r + c2 * 72 + icp * 4;
#pragma unroll
        for (int j = 0; j < 9; ++j) {
            double2 a = *(const double2*)&wb[j * 8];
            double2 c = *(const double2*)&wb[j * 8 + 2];
            wgt[j][0] = a.x; wgt[j][1] = a.y; wgt[j][2] = c.x; wgt[j][3] = c.y;
        }
    }
    const double bias2 = (double)b2[c2];

    // phase A: zero padded buffers
    for (int i = t; i < 900; i += 256) xs[i] = 0.f;
    for (int i = t; i < 16 * 16 * H1PAD; i += 256) h1s[i] = 0.0;
    __syncthreads();
    // phase B: fill xs interior
    for (int i = t; i < 784; i += 256) {
        const int yy = i / 28, xx = i - yy * 28;
        xs[(yy + 1) * 30 + (xx + 1)] = xb[i];
    }
    __syncthreads();

    // ---- stage 1: conv1 + relu + maxpool (f64) -> h1s interior
    {
        const int c1 = t & 7;
        double wc[9];
#pragma unroll
        for (int j = 0; j < 9; ++j) wc[j] = (double)w1[c1 * 9 + j];
        const double bb = (double)b1[c1];
        for (int q = (t >> 3); q < 196; q += 32) {
            const int py = q / 14, px = q - py * 14;
            double r2[4][4];
#pragma unroll
            for (int rr = 0; rr < 4; ++rr)
#pragma unroll
                for (int cc = 0; cc < 4; ++cc)
                    r2[rr][cc] = (double)xs[(2 * py + rr) * 30 + 2 * px + cc];
            double s[2][2] = {{bb, bb}, {bb, bb}};
#pragma unroll
            for (int dy = 0; dy < 2; ++dy)
#pragma unroll
                for (int dx = 0; dx < 2; ++dx)
#pragma unroll
                    for (int ky = 0; ky < 3; ++ky)
#pragma unroll
                        for (int kx = 0; kx < 3; ++kx)
                            s[dy][dx] = fma(r2[dy + ky][dx + kx], wc[ky * 3 + kx], s[dy][dx]);
            double mx = fmax(fmax(s[0][0], s[0][1]), fmax(s[1][0], s[1][1]));
            mx = fmax(mx, 0.0);   // pool(relu) == relu(maxpool), exactly
            h1s[((py + 1) * 16 + (px + 1)) * H1PAD + c1] = mx;
        }
    }
    __syncthreads();

    // ---- stage 2: conv2 + relu + maxpool (f64), weights in regs.
    // lane (c2, icp, g2): partial over 4 ic for q in {g2, g2+8, ...}
    for (int q = g2; q < 49; q += 8) {
        const int py = q / 7, px = q - py * 7;
        double s00 = 0, s01 = 0, s10 = 0, s11 = 0;
#pragma unroll
        for (int rr = 0; rr < 4; ++rr)
#pragma unroll
            for (int cc = 0; cc < 4; ++cc) {
                const double* hp = &h1s[((2 * py + rr) * 16 + 2 * px + cc) * H1PAD + icp * 4];
                double2 vl = *(const double2*)&hp[0];
                double2 vh = *(const double2*)&hp[2];
                const double v0 = vl.x, v1 = vl.y, v2 = vh.x, v3 = vh.y;
#pragma unroll
                for (int dy = 0; dy < 2; ++dy) {
                    const int ky = rr - dy;
                    if (ky < 0 || ky > 2) continue;   // constant-folds
#pragma unroll
                    for (int dx = 0; dx < 2; ++dx) {
                        const int kx = cc - dx;
                        if (kx < 0 || kx > 2) continue;
                        const int tap = ky * 3 + kx;
                        double acc = (dy == 0) ? (dx == 0 ? s00 : s01)
                                               : (dx == 0 ? s10 : s11);
                        acc = fma(v0, wgt[tap][0], acc);
                        acc = fma(v1, wgt[tap][1], acc);
                        acc = fma(v2, wgt[tap][2], acc);
                        acc = fma(v3, wgt[tap][3], acc);
                        if (dy == 0) { if (dx == 0) s00 = acc; else s01 = acc; }
                        else         { if (dx == 0) s10 = acc; else s11 = acc; }
                    }
                }
            }
        // combine ic halves (partner lane t^8, same wave)
        s00 += __shfl_xor(s00, 8);
        s01 += __shfl_xor(s01, 8);
        s10 += __shfl_xor(s10, 8);
        s11 += __shfl_xor(s11, 8);
        if (icp == 0) {
            double mx = fmax(fmax(s00, s01), fmax(s10, s11));
            mx = fmax(bias2 + mx, 0.0);
            h2s[c2 * 49 + q] = mx;
        }
    }
    __syncthreads();

    // writeout
    if (F64OUT) {
        double2* dst = (double2*)((double*)flatv + (size_t)b * 784);
        const double2* src = (const double2*)h2s;
        for (int i = t; i < 392; i += 256) dst[i] = src[i];
    } else {
        float* dst = (float*)flatv + (size_t)b * 784;
        for (int i = t; i < 784; i += 256) dst[i] = (float)h2s[i];
    }
}

// ---------------------------------------------------------------------------
// Kernel 2: streaming FC1 (784->64, relu) + FC2 (64->4) + BN stat partials.
// 2048 blocks x 256 thr; block = 4 rows staged in LDS (f64), thread = (col o,
// row-slot s). Row value is wave-uniform (LDS broadcast); weights coalesced
// via pre-transposed w1t. No atomics: per-block partials to psum.
// ---------------------------------------------------------------------------
template <bool F64IN>
__global__ __launch_bounds__(256) void fc_kernel(
    const void* __restrict__ flatv, const float* __restrict__ w1t,
    const float* __restrict__ fc1b,
    const float* __restrict__ fc2w, const float* __restrict__ fc2b,
    double* __restrict__ proj, double* __restrict__ psum) {

    __shared__ __align__(16) double rows[FC_ROWS][784];
    __shared__ __align__(16) double Hs[FC_ROWS][64];
    __shared__ double w2t[256];   // [o][kc] fc2 transposed

    const int t = threadIdx.x;
    const int row0 = blockIdx.x * FC_ROWS;

    w2t[t] = (double)fc2w[(t & 3) * 64 + (t >> 2)];
    // stage rows (coalesced)
    for (int i = t; i < FC_ROWS * 784; i += 256) {
        const int r = i / 784, k = i - r * 784;
        double v;
        if (F64IN) v = ((const double*)flatv)[(size_t)(row0 + r) * 784 + k];
        else       v = (double)((const float*)flatv)[(size_t)(row0 + r) * 784 + k];
        rows[r][k] = v;
    }
    __syncthreads();

    const int o = t & 63, s = t >> 6;
    const double* rp = rows[s];
    double acc0 = 0.0, acc1 = 0.0;
    for (int k = 0; k < 784; k += 4) {
        double2 x01 = *(const double2*)&rp[k];
        double2 x23 = *(const double2*)&rp[k + 2];
        const float wa = w1t[(k + 0) * 64 + o];
        const float wb = w1t[(k + 1) * 64 + o];
        const float wc = w1t[(k + 2) * 64 + o];
        const float wd = w1t[(k + 3) * 64 + o];
        acc0 = fma(x01.x, (double)wa, acc0);
        acc1 = fma(x01.y, (double)wb, acc1);
        acc0 = fma(x23.x, (double)wc, acc0);
        acc1 = fma(x23.y, (double)wd, acc1);
    }
    Hs[s][o] = fmax((acc0 + acc1) + (double)fc1b[o], 0.0);
    __syncthreads();

    if (t < 16) {
        const int r = t >> 2, kc = t & 3;
        double sv = (double)fc2b[kc];
#pragma unroll 8
        for (int c = 0; c < 64; ++c) sv = fma(Hs[r][c], w2t[c * 4 + kc], sv);
        proj[(size_t)(row0 + r) * 4 + kc] = sv;
        double ssum = sv, sq = sv * sv;
        ssum += __shfl_xor(ssum, 4);  sq += __shfl_xor(sq, 4);
        ssum += __shfl_xor(ssum, 8);  sq += __shfl_xor(sq, 8);
        if (t < 4) {
            psum[(size_t)blockIdx.x * 8 + t] = ssum;
            psum[(size_t)blockIdx.x * 8 + 4 + t] = sq;
        }
    }
}

// ---------------------------------------------------------------------------
// Kernel 2b: reduce per-block stat partials -> stats[8]
// ---------------------------------------------------------------------------
__global__ __launch_bounds__(256) void reduce_stats(
    const double* __restrict__ psum, double* __restrict__ stats) {
    __shared__ double red[256];
    const int t = threadIdx.x;
    const int c = t & 7, i0 = t >> 3;   // 32 strides per channel
    double v = 0.0;
    for (int i = i0; i < FC_NBLK; i += 32) v += psum[(size_t)i * 8 + c];
    red[t] = v;
    __syncthreads();
    if (t < 8) {
        double sacc = 0.0;
        for (int j = 0; j < 32; ++j) sacc += red[t + 8 * j];
        stats[t] = sacc;
    }
}

// ---------------------------------------------------------------------------
// Kernel 3: BatchNorm + row L2-normalize, f64. Emits pb32/pn32 (fast path)
// and pn64 (exact path for borderline fid rechecks).
// ---------------------------------------------------------------------------
__global__ __launch_bounds__(256) void bn_kernel(
    const double* __restrict__ proj, const double* __restrict__ stats,
    const float* __restrict__ gamma, const float* __restrict__ beta,
    float* __restrict__ pb32, float* __restrict__ pn32,
    double* __restrict__ pn64) {

    const int i = blockIdx.x * 256 + threadIdx.x;
    double2 p01 = ((const double2*)proj)[2 * i];
    double2 p23 = ((const double2*)proj)[2 * i + 1];
    double pv[4] = {p01.x, p01.y, p23.x, p23.y};
    double o[4];
#pragma unroll
    for (int k = 0; k < 4; ++k) {
        double mean = stats[k] * (1.0 / 8192.0);
        double var  = stats[4 + k] * (1.0 / 8192.0) - mean * mean;
        double inv  = 1.0 / sqrt(var + 1e-5);
        o[k] = (pv[k] - mean) * inv * (double)gamma[k] + (double)beta[k];
    }
    double nrm = sqrt(o[0] * o[0] + o[1] * o[1] + o[2] * o[2] + o[3] * o[3]);
    double innv = 1.0 / (nrm + 1e-12);
    ((float4*)pb32)[i] = make_float4((float)o[0], (float)o[1], (float)o[2], (float)o[3]);
    double n0 = o[0] * innv, n1 = o[1] * innv, n2 = o[2] * innv, n3 = o[3] * innv;
    ((float4*)pn32)[i] = make_float4((float)n0, (float)n1, (float)n2, (float)n3);
    double2* pd = (double2*)(pn64 + (size_t)i * 4);
    pd[0] = make_double2(n0, n1);
    pd[1] = make_double2(n2, n3);
}

// ---------------------------------------------------------------------------
// Kernel 4: O(B^2) adjacency. fp32 fast path with +-2e-4 guard band around
// 0.9; borderline pairs recheck in f64 from pn64 (exact flip decisions).
// 64 rows/block (4 rows/lane x 16 j-lanes), LDS-staged j chunks of 1024.
// ---------------------------------------------------------------------------
#define CHUNK 1024
__global__ __launch_bounds__(256) void adj_kernel(
    const float* __restrict__ pn32, const float* __restrict__ pb32,
    const double* __restrict__ pn64,
    float* __restrict__ wp32, float* __restrict__ sd) {

    __shared__ __align__(16) float4 pns[CHUNK];
    __shared__ __align__(16) float4 pbs[CHUNK];
    __shared__ float bpart[16];

    const int t = threadIdx.x;
    const int tg = t & 15, g = t >> 4;
    const int rowb = blockIdx.x * 64 + g * 4;

    float4 pni[4];
#pragma unroll
    for (int r = 0; r < 4; ++r) pni[r] = ((const float4*)pn32)[rowb + r];
    float w[4][4] = {};

    for (int base = 0; base < 8192; base += CHUNK) {
        __syncthreads();
        for (int i = t; i < CHUNK; i += 256) {
            pns[i] = ((const float4*)pn32)[base + i];
            pbs[i] = ((const float4*)pb32)[base + i];
        }
        __syncthreads();
        for (int jj = 0; jj < CHUNK / 16; ++jj) {
            const int jl = jj * 16 + tg;
            const int j = base + jl;
            float4 q = pns[jl];
            float4 pj = pbs[jl];
#pragma unroll
            for (int r = 0; r < 4; ++r) {
                float d = fmaf(pni[r].x, q.x, fmaf(pni[r].y, q.y,
                          fmaf(pni[r].z, q.z, pni[r].w * q.w)));
                float fid = d * d;
                bool ok;
                if (fabsf(fid - 0.9f) < 2e-4f) {   // rare: exact recheck
                    const double2* pr = (const double2*)(pn64 + (size_t)(rowb + r) * 4);
                    const double2* pq = (const double2*)(pn64 + (size_t)j * 4);
                    double2 r0 = pr[0], r1 = pr[1], q0 = pq[0], q1 = pq[1];
                    double dd = fma(r0.x, q0.x, fma(r0.y, q0.y,
                                fma(r1.x, q1.x, r1.y * q1.y)));
                    ok = (dd * dd >= 0.9);
                } else {
                    ok = (fid >= 0.9f);
                }
                float m = (ok && j != (rowb + r)) ? 1.f : 0.f;
                w[r][0] = fmaf(m, pj.x, w[r][0]);
                w[r][1] = fmaf(m, pj.y, w[r][1]);
                w[r][2] = fmaf(m, pj.z, w[r][2]);
                w[r][3] = fmaf(m, pj.w, w[r][3]);
            }
        }
    }
#pragma unroll
    for (int m = 1; m < 16; m <<= 1)
#pragma unroll
        for (int r = 0; r < 4; ++r) {
            w[r][0] += __shfl_xor(w[r][0], m);
            w[r][1] += __shfl_xor(w[r][1], m);
            w[r][2] += __shfl_xor(w[r][2], m);
            w[r][3] += __shfl_xor(w[r][3], m);
        }
    if (tg == 0) {
        float ds_ = 0.f;
#pragma unroll
        for (int r = 0; r < 4; ++r) {
            ((float4*)wp32)[rowb + r] = make_float4(w[r][0], w[r][1], w[r][2], w[r][3]);
            float4 pbv = ((const float4*)pb32)[rowb + r];
            float d0 = pbv.x - w[r][0], d1 = pbv.y - w[r][1];
            float d2 = pbv.z - w[r][2], d3 = pbv.w - w[r][3];
            ds_ += d0 * d0 + d1 * d1 + d2 * d2 + d3 * d3;
        }
        bpart[g] = ds_;
    }
    __syncthreads();
    if (t == 0) {
        float sacc = 0.f;
#pragma unroll
        for (int i = 0; i < 16; ++i) sacc += bpart[i];
        atomicAdd(sd, sacc);
    }
}

// ---------------------------------------------------------------------------
// Kernel 5: epilogue -> probs
// ---------------------------------------------------------------------------
__global__ __launch_bounds__(256) void final_kernel(
    const float* __restrict__ pb32, const float* __restrict__ wp32,
    const float* __restrict__ sd, float* __restrict__ out) {

    const int i = blockIdx.x * 256 + threadIdx.x;
    const double kv = exp(-(double)sd[0]);
    float4 p = ((const float4*)pb32)[i];
    float4 w = ((const float4*)wp32)[i];
    double logit = (double)p.x + p.y + p.z + p.w
                 + (double)w.x + w.y + w.z + w.w + kv;
    double pr = 1.0 / (1.0 + exp(-logit));
    *(float2*)&out[2 * i] = make_float2((float)pr, (float)(1.0 - pr));
}

// ---------------------------------------------------------------------------
extern "C" void kernel_launch(void* const* d_in, const int* in_sizes, int n_in,
                              void* d_out, int out_size, void* d_ws, size_t ws_size,
                              hipStream_t stream) {
    const float* x     = (const float*)d_in[0];
    const float* c1w   = (const float*)d_in[1];
    const float* c1b   = (const float*)d_in[2];
    const float* c2w   = (const float*)d_in[3];
    const float* c2b   = (const float*)d_in[4];
    const float* fc1w  = (const float*)d_in[5];
    const float* fc1b  = (const float*)d_in[6];
    const float* fc2w  = (const float*)d_in[7];
    const float* fc2b  = (const float*)d_in[8];
    const float* gamma = (const float*)d_in[9];
    const float* beta  = (const float*)d_in[10];
    float* out = (float*)d_out;

    char* ws = (char*)d_ws;
    double* stats = (double*)(ws + OFF_STATS);
    float*  sd    = (float*)(ws + OFF_SD);
    double* proj  = (double*)(ws + OFF_PROJ);
    double* pn64  = (double*)(ws + OFF_PN64);
    float*  pb32  = (float*)(ws + OFF_PB32);
    float*  pn32  = (float*)(ws + OFF_PN32);
    float*  wp32  = (float*)(ws + OFF_WP32);
    double* w2r   = (double*)(ws + OFF_W2R);
    float*  w1t   = (float*)(ws + OFF_W1T);
    double* psum  = (double*)(ws + OFF_PSUM);
    void*   flat  = (void*)(ws + OFF_FLAT);

    // deterministic per-deployment branch (ws_size constant across calls)
    const bool f64flat = ws_size >= (size_t)OFF_FLAT + FLAT64_BYTES;

    setup_kernel<<<64, 256, 0, stream>>>(c2w, fc1w, w2r, w1t, sd);
    if (f64flat) {
        conv_fused<true><<<B_IMG, 256, 0, stream>>>(x, c1w, c1b, w2r, c2b, flat);
        fc_kernel<true><<<FC_NBLK, 256, 0, stream>>>(flat, w1t, fc1b, fc2w, fc2b, proj, psum);
    } else {
        conv_fused<false><<<B_IMG, 256, 0, stream>>>(x, c1w, c1b, w2r, c2b, flat);
        fc_kernel<false><<<FC_NBLK, 256, 0, stream>>>(flat, w1t, fc1b, fc2w, fc2b, proj, psum);
    }
    reduce_stats<<<1, 256, 0, stream>>>(psum, stats);
    bn_kernel<<<B_IMG / 256, 256, 0, stream>>>(proj, stats, gamma, beta, pb32, pn32, pn64);
    adj_kernel<<<B_IMG / 64, 256, 0, stream>>>(pn32, pb32, pn64, wp32, sd);
    final_kernel<<<B_IMG / 256, 256, 0, stream>>>(pb32, wp32, sd, out);
}